// Round 8
// baseline (75.973 us; speedup 1.0000x reference)
//
#include <hip/hip_runtime.h>
#include <hip/hip_bf16.h>

#define EPS 1e-12f
// C_EXP = (1/0.07)*log2(e); features stored pre-scaled by sqrt(C_EXP) so the
// MFMA output is already exp2-ready: exp(sim/T) == exp2(fs_i . fs_j).
#define SQRT_C_EXP 4.53981597f
#define M_LN2F 0.69314718056f
#define NUM_CLASSES 16
#define CS_BLOCKS 256

#define BM 128          // rows per denom block
#define BN 128          // cols per chunk
#define KD 128          // feature dim
#define NCHUNK 16       // chunks per colgroup (2048 cols)
#define NCOLG 4         // colgroups
#define NPART 16        // NCOLG * 4 wave-columns

typedef __attribute__((ext_vector_type(4))) float f32x4;
typedef __attribute__((ext_vector_type(8))) short bf16x8;

__device__ __forceinline__ float bf2f(ushort u) {
    unsigned int x = ((unsigned int)u) << 16;
    return __uint_as_float(x);
}

// Swizzled LDS fragment address: element (r, slot) of a [rows][128] bf16 tile,
// slot = 16B chunk within the 256B row. Swizzle: slot ^= (r&7).
__device__ __forceinline__ const bf16x8* lds_frag(const ushort* base, int r, int slot) {
    int sw = slot ^ (r & 7);
    return reinterpret_cast<const bf16x8*>(
        reinterpret_cast<const char*>(base) + r * 256 + sw * 16);
}

// ---------------- Kernel A: normalize (pre-scaled) + class partials --------
// 256 blocks x 32 rows; 4 waves x 8 rows. Stores fs = bf16(f_norm*sqrt(C_EXP)),
// sq_s[r] = ||fs||^2, per-block class partials (no atomics, no memset).
__global__ __launch_bounds__(256) void norm_classsum(
    const float* __restrict__ feat,
    const int* __restrict__ labels,
    ushort* __restrict__ fb,
    float* __restrict__ sq,
    float* __restrict__ g_part,     // [CS_BLOCKS][16][128]
    float* __restrict__ cnt_part,   // [CS_BLOCKS][16]
    int N) {
    __shared__ float lg[4][NUM_CLASSES][128];   // 32 KB, per-wave regions
    __shared__ float lc[4][NUM_CLASSES];
    const int tid  = threadIdx.x;
    const int lane = tid & 63;
    const int w    = tid >> 6;

    float* myg = &lg[w][0][0];
    for (int i = lane; i < NUM_CLASSES * 128; i += 64) myg[i] = 0.f;
    if (lane < NUM_CLASSES) lc[w][lane] = 0.f;
    // each wave touches only its own region before the barrier

    const int r0 = blockIdx.x * 32 + w * 8;
    for (int rr = 0; rr < 8; rr++) {
        const int r = r0 + rr;
        const float2 v = *reinterpret_cast<const float2*>(feat + (size_t)r * KD + lane * 2);
        float s = v.x * v.x + v.y * v.y;
        #pragma unroll
        for (int off = 1; off < 64; off <<= 1) s += __shfl_xor(s, off);
        const float scale = SQRT_C_EXP / fmaxf(sqrtf(s), EPS);

        __hip_bfloat16 h0 = __float2bfloat16(v.x * scale);
        __hip_bfloat16 h1 = __float2bfloat16(v.y * scale);
        ushort u0 = *reinterpret_cast<ushort*>(&h0);
        ushort u1 = *reinterpret_cast<ushort*>(&h1);
        unsigned int pack = (unsigned int)u0 | ((unsigned int)u1 << 16);
        *reinterpret_cast<unsigned int*>(fb + (size_t)r * KD + lane * 2) = pack;

        float q0 = bf2f(u0), q1 = bf2f(u1);
        float q = q0 * q0 + q1 * q1;
        #pragma unroll
        for (int off = 1; off < 64; off <<= 1) q += __shfl_xor(q, off);
        if (lane == 0) sq[r] = q;                 // sq_s = C_EXP*||f||^2

        const int lab = labels[r];                // wave-uniform
        lg[w][lab][lane * 2]     += q0;           // accumulate scaled values
        lg[w][lab][lane * 2 + 1] += q1;
        if (lane == 0) lc[w][lab] += 1.f;
    }
    __syncthreads();

    const float* flat = &lg[0][0][0];
    for (int i = tid; i < NUM_CLASSES * 128; i += 256)
        g_part[(size_t)blockIdx.x * 2048 + i] =
            flat[i] + flat[2048 + i] + flat[4096 + i] + flat[6144 + i];
    if (tid < NUM_CLASSES)
        cnt_part[blockIdx.x * NUM_CLASSES + tid] =
            lc[0][tid] + lc[1][tid] + lc[2][tid] + lc[3][tid];
}

// ---------------- Kernel A2: reduce class partials --------------------------
// 16 blocks (one per class) x 256 threads.
__global__ void classreduce_kernel(const float* __restrict__ g_part,
                                   const float* __restrict__ cnt_part,
                                   float* __restrict__ g,
                                   float* __restrict__ cntf) {
    const int c   = blockIdx.x;
    const int tid = threadIdx.x;
    const int d   = tid & 127;
    const int seg = tid >> 7;            // 0..1
    __shared__ float tmp[2][128];
    __shared__ float sc[4];

    float acc = 0.f;
    for (int b = seg * 128; b < seg * 128 + 128; b++)
        acc += g_part[(size_t)b * 2048 + c * 128 + d];
    tmp[seg][d] = acc;

    float cv = cnt_part[tid * NUM_CLASSES + c];
    #pragma unroll
    for (int off = 1; off < 64; off <<= 1) cv += __shfl_xor(cv, off);
    if ((tid & 63) == 0) sc[tid >> 6] = cv;
    __syncthreads();
    if (tid < 128) g[c * 128 + tid] = tmp[0][tid] + tmp[1][tid];
    if (tid == 0)  cntf[c] = sc[0] + sc[1] + sc[2] + sc[3];
}

// ---------------- Kernel B: denom partials, A-in-registers ------------------
// Grid (4 colgroups, 64 rowblocks) = 256 blocks, 512 threads = 8 waves (2x4).
// Wave tile 64x32. A-frags (16 x b128 = 64 VGPR) loaded ONCE from LDS; per
// chunk only B is read from LDS: 0.25 ds_reads/MFMA -> matrix-bound.
// LDS = A 32KB + B dbuf 2x32KB = 96KB (1 block/CU).
__global__ __launch_bounds__(512) void supcon_denom(
    const ushort* __restrict__ fb,
    float* __restrict__ denom_part,
    int N) {

    __shared__ __align__(16) ushort As[BM * KD];        // 32 KB
    __shared__ __align__(16) ushort Bs[2][BN * KD];     // 2 x 32 KB

    const int tid  = threadIdx.x;
    const int lane = tid & 63;
    const int w    = tid >> 6;        // 0..7
    const int wr   = w >> 2;          // 0..1 (64-row half)
    const int wc   = w & 3;           // 0..3 (32-col quarter)
    const int r16  = lane & 15;
    const int g4   = lane >> 4;       // 0..3

    const int rowbase = blockIdx.y * BM;
    const int col0    = blockIdx.x * (BN * NCHUNK);

    // ---- stage A tile (32KB) + B chunk 0 (32KB) ----
    {
        const ushort* gA = fb + (size_t)rowbase * KD;
        #pragma unroll
        for (int i = 0; i < 4; i++) {
            int c = i * 512 + tid;                  // 16B chunk index
            bf16x8 v = *reinterpret_cast<const bf16x8*>(gA + c * 8);
            int dst = c ^ ((c >> 4) & 7);
            *reinterpret_cast<bf16x8*>(&As[dst * 8]) = v;
        }
        const ushort* gB = fb + (size_t)col0 * KD;
        #pragma unroll
        for (int i = 0; i < 4; i++) {
            int c = i * 512 + tid;
            bf16x8 v = *reinterpret_cast<const bf16x8*>(gB + c * 8);
            int dst = c ^ ((c >> 4) & 7);
            *reinterpret_cast<bf16x8*>(&Bs[0][dst * 8]) = v;
        }
    }
    __syncthreads();

    // ---- A fragments for the whole block, resident in registers ----
    bf16x8 a[4][4];                   // [ks][m], statically indexed only
    #pragma unroll
    for (int ks = 0; ks < 4; ks++) {
        const int slot = ks * 4 + g4;
        #pragma unroll
        for (int m = 0; m < 4; m++)
            a[ks][m] = *lds_frag(As, wr * 64 + m * 16 + r16, slot);
    }

    float pd[4][4];                   // [m][i] per-row exp-sum partials
    #pragma unroll
    for (int m = 0; m < 4; m++)
        #pragma unroll
        for (int i = 0; i < 4; i++) pd[m][i] = 0.f;

    int cur = 0;
    for (int c = 0; c < NCHUNK; c++) {
        // issue next-chunk global loads early (hidden under MFMA+exp)
        bf16x8 pre0, pre1, pre2, pre3;
        if (c + 1 < NCHUNK) {
            const ushort* gB = fb + (size_t)(col0 + (c + 1) * BN) * KD;
            pre0 = *reinterpret_cast<const bf16x8*>(gB + (0 * 512 + tid) * 8);
            pre1 = *reinterpret_cast<const bf16x8*>(gB + (1 * 512 + tid) * 8);
            pre2 = *reinterpret_cast<const bf16x8*>(gB + (2 * 512 + tid) * 8);
            pre3 = *reinterpret_cast<const bf16x8*>(gB + (3 * 512 + tid) * 8);
        }

        f32x4 acc[4][2];
        #pragma unroll
        for (int m = 0; m < 4; m++)
            #pragma unroll
            for (int n = 0; n < 2; n++) acc[m][n] = f32x4{0.f, 0.f, 0.f, 0.f};

        const ushort* bbase = Bs[cur];
        #pragma unroll
        for (int ks = 0; ks < 4; ks++) {
            const int slot = ks * 4 + g4;
            bf16x8 bv[2];
            #pragma unroll
            for (int n = 0; n < 2; n++)
                bv[n] = *lds_frag(bbase, wc * 32 + n * 16 + r16, slot);
            #pragma unroll
            for (int m = 0; m < 4; m++)
                #pragma unroll
                for (int n = 0; n < 2; n++)
                    acc[m][n] = __builtin_amdgcn_mfma_f32_16x16x32_bf16(a[ks][m], bv[n], acc[m][n], 0, 0, 0);
        }

        // fs pre-scaling makes acc exp2-ready: no per-element multiply
        #pragma unroll
        for (int m = 0; m < 4; m++)
            #pragma unroll
            for (int n = 0; n < 2; n++)
                #pragma unroll
                for (int i = 0; i < 4; i++)
                    pd[m][i] += __builtin_amdgcn_exp2f(acc[m][n][i]);

        if (c + 1 < NCHUNK) {
            ushort* dstb = Bs[cur ^ 1];
            int ch;
            ch = 0 * 512 + tid; *reinterpret_cast<bf16x8*>(&dstb[(ch ^ ((ch >> 4) & 7)) * 8]) = pre0;
            ch = 1 * 512 + tid; *reinterpret_cast<bf16x8*>(&dstb[(ch ^ ((ch >> 4) & 7)) * 8]) = pre1;
            ch = 2 * 512 + tid; *reinterpret_cast<bf16x8*>(&dstb[(ch ^ ((ch >> 4) & 7)) * 8]) = pre2;
            ch = 3 * 512 + tid; *reinterpret_cast<bf16x8*>(&dstb[(ch ^ ((ch >> 4) & 7)) * 8]) = pre3;
        }
        __syncthreads();
        cur ^= 1;
    }

    // reduce across the 16 lanes sharing the same rows, write partials
    #pragma unroll
    for (int off = 1; off < 16; off <<= 1)
        #pragma unroll
        for (int m = 0; m < 4; m++)
            #pragma unroll
            for (int i = 0; i < 4; i++)
                pd[m][i] += __shfl_xor(pd[m][i], off);

    if (r16 == 0) {
        const int part = blockIdx.x * 4 + wc;   // 0..15
        #pragma unroll
        for (int m = 0; m < 4; m++)
            #pragma unroll
            for (int i = 0; i < 4; i++) {
                int r = rowbase + wr * 64 + m * 16 + g4 * 4 + i;
                denom_part[(size_t)r * NPART + part] = pd[m][i];
            }
    }
}

// ---------------- Kernel C: per-row loss ------------------------------------
__global__ void rowloss_kernel(const ushort* __restrict__ fb,
                               const int* __restrict__ labels,
                               const float* __restrict__ denom_part,
                               const float* __restrict__ sq,
                               const float* __restrict__ g,
                               const float* __restrict__ cntf,
                               float* __restrict__ rowloss,
                               int N) {
    int r    = (blockIdx.x * blockDim.x + threadIdx.x) >> 6;
    int lane = threadIdx.x & 63;
    if (r >= N) return;
    int lab = labels[r];
    unsigned int pk = *reinterpret_cast<const unsigned int*>(fb + (size_t)r * KD + lane * 2);
    float f0 = bf2f((ushort)(pk & 0xffff));
    float f1 = bf2f((ushort)(pk >> 16));
    const float2 gv = *reinterpret_cast<const float2*>(g + lab * 128 + lane * 2);
    float p = f0 * gv.x + f1 * gv.y;          // p_s = C_EXP * (f . g)
    #pragma unroll
    for (int off = 1; off < 64; off <<= 1) p += __shfl_xor(p, off);

    float dsum = (lane < NPART) ? denom_part[(size_t)r * NPART + lane] : 0.f;
    #pragma unroll
    for (int off = 1; off < NPART; off <<= 1) dsum += __shfl_xor(dsum, off);

    if (lane == 0) {
        float sqr    = sq[r];                              // sq_s
        float possum = (p - sqr) * M_LN2F;                 // (p_s-sq_s)/(C_EXP*T)
        float cnt    = cntf[lab] - 1.0f;
        float dn     = dsum - __builtin_amdgcn_exp2f(sqr); // remove diagonal
        rowloss[r]   = -(possum - cnt * logf(dn + EPS)) / (cnt + EPS);
    }
}

// ---------------- Kernel D: mean (deterministic single-block reduce) --------
__global__ void reduce_kernel(const float* __restrict__ rowloss,
                              float* __restrict__ out, int N) {
    __shared__ float sdata[16];
    float s = 0.f;
    for (int r = threadIdx.x; r < N; r += blockDim.x) s += rowloss[r];
    #pragma unroll
    for (int off = 1; off < 64; off <<= 1) s += __shfl_xor(s, off);
    int wv = threadIdx.x >> 6;
    if ((threadIdx.x & 63) == 0) sdata[wv] = s;
    __syncthreads();
    if (threadIdx.x == 0) {
        float t = 0.f;
        int nw = (int)(blockDim.x >> 6);
        for (int i = 0; i < nw; i++) t += sdata[i];
        out[0] = t / (float)N;
    }
}

extern "C" void kernel_launch(void* const* d_in, const int* in_sizes, int n_in,
                              void* d_out, int out_size, void* d_ws, size_t ws_size,
                              hipStream_t stream) {
    const float* feat = (const float*)d_in[0];
    const int* labels = (const int*)d_in[1];
    const int N = in_sizes[1];

    char* ws = (char*)d_ws;
    size_t off = 0;
    ushort* fb        = (ushort*)(ws + off); off += (size_t)N * KD * sizeof(ushort);
    float* sq         = (float*)(ws + off);  off += (size_t)N * sizeof(float);
    float* g_part     = (float*)(ws + off);  off += (size_t)CS_BLOCKS * NUM_CLASSES * KD * sizeof(float);
    float* cnt_part   = (float*)(ws + off);  off += (size_t)CS_BLOCKS * NUM_CLASSES * sizeof(float);
    float* g          = (float*)(ws + off);  off += (size_t)NUM_CLASSES * KD * sizeof(float);
    float* cntf       = (float*)(ws + off);  off += (size_t)NUM_CLASSES * sizeof(float);
    float* denom_part = (float*)(ws + off);  off += (size_t)N * NPART * sizeof(float);
    float* rowloss    = (float*)(ws + off);

    norm_classsum<<<CS_BLOCKS, 256, 0, stream>>>(feat, labels, fb, sq, g_part, cnt_part, N);
    classreduce_kernel<<<NUM_CLASSES, 256, 0, stream>>>(g_part, cnt_part, g, cntf);

    dim3 grid(NCOLG, N / BM);                         // (4, 64) = 256 blocks
    supcon_denom<<<grid, 512, 0, stream>>>(fb, denom_part, N);

    rowloss_kernel<<<(N + 3) / 4, 256, 0, stream>>>(fb, labels, denom_part, sq, g, cntf, rowloss, N);
    reduce_kernel<<<1, 1024, 0, stream>>>(rowloss, (float*)d_out, N);
}